// Round 2
// baseline (1771.048 us; speedup 1.0000x reference)
//
#include <hip/hip_runtime.h>

// Problem constants (reference: B=4, N=50000, F_IN=F_OUT=64, E=800000)
// All float tensors are float32 (reference dtype); indices are int32.
#define NB 4
#define NN 50000
#define FF 64

// pre[n][f] = sum_k x[n][k] * W[k][f]  for one batch slice of x.
// Block = 256 threads = 4 rows x 64 feature-columns. W staged in LDS.
__global__ void gemm_xw_kernel(const float* __restrict__ x,
                               const float* __restrict__ W,
                               float* __restrict__ pre) {
    __shared__ float Ws[FF][FF];   // 16 KB
    __shared__ float xs[4][FF];    // 1 KB
    const int tid = threadIdx.x;

    // Load W: 4096 elems / 256 threads = 16 each, coalesced float4s via unroll.
#pragma unroll
    for (int i = 0; i < 16; ++i) {
        int idx = tid + i * 256;
        Ws[idx >> 6][idx & 63] = W[idx];
    }
    const int row0 = blockIdx.x * 4;         // NN % 4 == 0 -> no bounds check
    const int r = tid >> 6;
    const int f = tid & 63;
    xs[r][f] = x[(size_t)(row0 + r) * FF + f];
    __syncthreads();

    float a = 0.f;
#pragma unroll
    for (int k = 0; k < FF; ++k) a += xs[r][k] * Ws[k][f];  // xs broadcast, Ws conflict-free
    pre[(size_t)(row0 + r) * FF + f] = a;
}

// For each edge e: acc[rows[e]][:] += vals[e] * pre[cols[e]][:]
// 64 threads per edge (one per feature). Scalar fp32 atomics into acc.
__global__ void spmm_atomic_kernel(const int* __restrict__ rows,
                                   const int* __restrict__ cols,
                                   const float* __restrict__ vals,
                                   const float* __restrict__ pre,
                                   float* __restrict__ acc, int E) {
    const int idx = blockIdx.x * blockDim.x + threadIdx.x;
    const int e = idx >> 6;
    if (e >= E) return;
    const int f = idx & 63;
    const int r = rows[e];            // wave-uniform within the 64-lane group -> s-load
    const int c = cols[e];
    const float v = vals[e];
    atomicAdd(&acc[(size_t)r * FF + f], v * pre[(size_t)c * FF + f]);
}

// out = relu(acc + bias), one batch slice.
__global__ void finalize_kernel(const float* __restrict__ acc,
                                const float* __restrict__ bias,
                                float* __restrict__ out, int n) {
    const int idx = blockIdx.x * blockDim.x + threadIdx.x;
    if (idx >= n) return;
    float v = acc[idx] + bias[idx & 63];
    out[idx] = v > 0.f ? v : 0.f;
}

extern "C" void kernel_launch(void* const* d_in, const int* in_sizes, int n_in,
                              void* d_out, int out_size, void* d_ws, size_t ws_size,
                              hipStream_t stream) {
    const float* x     = (const float*)d_in[0];
    const int*   rows1 = (const int*)d_in[1];
    const int*   cols1 = (const int*)d_in[2];
    const float* vals1 = (const float*)d_in[3];
    const int*   rows2 = (const int*)d_in[4];
    const int*   cols2 = (const int*)d_in[5];
    const float* vals2 = (const float*)d_in[6];
    const float* W1    = (const float*)d_in[7];
    const float* W2    = (const float*)d_in[8];
    const float* bias  = (const float*)d_in[9];
    float* out = (float*)d_out;

    const int E = in_sizes[1];
    const size_t slice = (size_t)NN * FF;           // 3.2M elems per batch slice

    // Workspace layout (per-batch reuse): pre 12.8MB fp32, acc 12.8MB fp32.
    float* pre = (float*)d_ws;
    float* acc = pre + slice;

    const int gemm_blocks  = NN / 4;
    const int spmm_blocks  = (int)(((size_t)E * FF + 255) / 256);
    const int final_blocks = (int)((slice + 255) / 256);

    for (int b = 0; b < NB; ++b) {
        const float* xb   = x + (size_t)b * slice;
        float*       outb = out + (size_t)b * slice;

        hipMemsetAsync(acc, 0, slice * sizeof(float), stream);
        gemm_xw_kernel<<<gemm_blocks, 256, 0, stream>>>(xb, W1, pre);
        spmm_atomic_kernel<<<spmm_blocks, 256, 0, stream>>>(rows1, cols1, vals1, pre, acc, E);
        gemm_xw_kernel<<<gemm_blocks, 256, 0, stream>>>(xb, W2, pre);
        spmm_atomic_kernel<<<spmm_blocks, 256, 0, stream>>>(rows2, cols2, vals2, pre, acc, E);
        finalize_kernel<<<final_blocks, 256, 0, stream>>>(acc, bias, outb, (int)slice);
    }
}

// Round 3
// 1106.884 us; speedup vs baseline: 1.6000x; 1.6000x over previous
//
#include <hip/hip_runtime.h>

// GCN layer: relu(A1·(xW1) + A2·(xW2) + b), B=4, N=50000, F=64, E=800000.
// All float tensors fp32; indices int32.
#define NB 4
#define NN 50000
#define FF 64

// ---------------- GEMM: pre[n][b][f] = sum_k x[b][n][k] * W[k][f] ----------
// Batch-INTERLEAVED output layout so one edge gather touches one contiguous
// 1024 B block (4 batches x 64 feats). Grid: (NN/16, NB). 16 nodes/block to
// amortize the 16 KB W stage.
__global__ void gemm_xw_batched(const float* __restrict__ x,
                                const float* __restrict__ W,
                                float* __restrict__ pre) {
    __shared__ float Ws[FF][FF];   // 16 KB
    __shared__ float xs[4][FF];
    const int tid = threadIdx.x;
    const int b = blockIdx.y;
#pragma unroll
    for (int i = 0; i < 16; ++i) {
        int idx = tid + i * 256;
        Ws[idx >> 6][idx & 63] = W[idx];
    }
    const int r = tid >> 6;        // 0..3
    const int f = tid & 63;
    const int base = blockIdx.x * 16;
    const float* xb = x + (size_t)b * NN * FF;
#pragma unroll
    for (int g = 0; g < 4; ++g) {
        const int row = base + g * 4 + r;
        __syncthreads();
        xs[r][f] = xb[(size_t)row * FF + f];
        __syncthreads();
        float a = 0.f;
#pragma unroll
        for (int k = 0; k < FF; ++k) a += xs[r][k] * Ws[k][f];
        pre[((size_t)row * NB + b) * FF + f] = a;   // contiguous 256 B per wave
    }
}

// ---------------- CSR build: histogram -> scan -> scatter -------------------
__global__ void hist_kernel(const int* __restrict__ rows, int* __restrict__ counts, int E) {
    const int e = blockIdx.x * blockDim.x + threadIdx.x;
    if (e < E) atomicAdd(&counts[rows[e]], 1);
}

// Single-block chunked exclusive scan over NN counts -> rowptr[NN+1], cursor.
__global__ void scan_kernel(const int* __restrict__ counts,
                            int* __restrict__ rowptr, int* __restrict__ cursor) {
    __shared__ int buf[256];
    __shared__ int carry;
    const int tid = threadIdx.x;
    if (tid == 0) carry = 0;
    __syncthreads();
    for (int base = 0; base < NN; base += 256) {
        const int i = base + tid;
        const int v = (i < NN) ? counts[i] : 0;
        buf[tid] = v;
        __syncthreads();
#pragma unroll
        for (int off = 1; off < 256; off <<= 1) {
            int t = (tid >= off) ? buf[tid - off] : 0;
            __syncthreads();
            buf[tid] += t;
            __syncthreads();
        }
        const int excl = buf[tid] - v + carry;   // exclusive prefix
        if (i < NN) { rowptr[i] = excl; cursor[i] = excl; }
        __syncthreads();
        if (tid == 0) carry += buf[255];
        __syncthreads();
    }
    if (tid == 0) rowptr[NN] = carry;            // == E
}

__global__ void scatter_kernel(const int* __restrict__ rows, const int* __restrict__ cols,
                               const float* __restrict__ vals, int* __restrict__ cursor,
                               int* __restrict__ cols_s, float* __restrict__ vals_s, int E) {
    const int e = blockIdx.x * blockDim.x + threadIdx.x;
    if (e >= E) return;
    const int pos = atomicAdd(&cursor[rows[e]], 1);
    cols_s[pos] = cols[e];
    vals_s[pos] = vals[e];
}

// ---------------- SpMM (CSR, atomic-free) -----------------------------------
// One 64-lane group per row; lane = feature. 4 accumulators = 4 batches.
// pass 0: out[b][r][f]  = sum            (support 1, covers every row)
// pass 1: out[b][r][f] += sum, +bias, relu (support 2, final)
__global__ void spmm_csr_kernel(const int* __restrict__ rowptr,
                                const int* __restrict__ cols_s,
                                const float* __restrict__ vals_s,
                                const float* __restrict__ pre,   // [N][4][64]
                                const float* __restrict__ bias,
                                float* __restrict__ out,         // [B][N][64]
                                int pass) {
    const int tid = blockIdx.x * blockDim.x + threadIdx.x;
    const int r = tid >> 6;
    if (r >= NN) return;
    const int f = tid & 63;
    float a0 = 0.f, a1 = 0.f, a2 = 0.f, a3 = 0.f;
    const int beg = rowptr[r], end = rowptr[r + 1];
    for (int j = beg; j < end; ++j) {
        const int c = cols_s[j];
        const float v = vals_s[j];
        const float* p = pre + (size_t)c * (NB * FF) + f;   // 1024 B block
        a0 += v * p[0];
        a1 += v * p[64];
        a2 += v * p[128];
        a3 += v * p[192];
    }
    const size_t o0 = (size_t)r * FF + f;
    const size_t s = (size_t)NN * FF;
    if (pass == 0) {
        out[o0] = a0; out[o0 + s] = a1; out[o0 + 2 * s] = a2; out[o0 + 3 * s] = a3;
    } else {
        const float bf = bias[f];
        float t0 = out[o0] + a0 + bf;
        float t1 = out[o0 + s] + a1 + bf;
        float t2 = out[o0 + 2 * s] + a2 + bf;
        float t3 = out[o0 + 3 * s] + a3 + bf;
        out[o0] = t0 > 0.f ? t0 : 0.f;
        out[o0 + s] = t1 > 0.f ? t1 : 0.f;
        out[o0 + 2 * s] = t2 > 0.f ? t2 : 0.f;
        out[o0 + 3 * s] = t3 > 0.f ? t3 : 0.f;
    }
}

extern "C" void kernel_launch(void* const* d_in, const int* in_sizes, int n_in,
                              void* d_out, int out_size, void* d_ws, size_t ws_size,
                              hipStream_t stream) {
    const float* x    = (const float*)d_in[0];
    const int*   rows[2] = { (const int*)d_in[1], (const int*)d_in[4] };
    const int*   cols[2] = { (const int*)d_in[2], (const int*)d_in[5] };
    const float* vals[2] = { (const float*)d_in[3], (const float*)d_in[6] };
    const float* Wm[2]   = { (const float*)d_in[7], (const float*)d_in[8] };
    const float* bias = (const float*)d_in[9];
    float* out = (float*)d_out;

    const int E = in_sizes[1];

    // Workspace layout (256 B aligned):
    //   pre      : NN*NB*FF fp32            = 51.2 MB
    //   counts   : NN int
    //   rowptr   : NN+1 int
    //   cursor   : NN int
    //   cols_s   : E int
    //   vals_s   : E fp32
    char* w = (char*)d_ws;
    auto align = [](size_t v) { return (v + 255) & ~(size_t)255; };
    float* pre    = (float*)w;                       w += align((size_t)NN * NB * FF * 4);
    int*   counts = (int*)w;                         w += align((size_t)NN * 4);
    int*   rowptr = (int*)w;                         w += align(((size_t)NN + 1) * 4);
    int*   cursor = (int*)w;                         w += align((size_t)NN * 4);
    int*   cols_s = (int*)w;                         w += align((size_t)E * 4);
    float* vals_s = (float*)w;

    const dim3 gemm_grid(NN / 16, NB);
    const int  edge_blocks = (E + 255) / 256;
    const int  spmm_blocks = (NN * FF + 255) / 256;   // NN/4 row-quads

    for (int s = 0; s < 2; ++s) {
        // dense: pre[n][b][f] = x[b][n][:] . W_s
        gemm_xw_batched<<<gemm_grid, 256, 0, stream>>>(x, Wm[s], pre);
        // CSR build for support s
        hipMemsetAsync(counts, 0, (size_t)NN * 4, stream);
        hist_kernel<<<edge_blocks, 256, 0, stream>>>(rows[s], counts, E);
        scan_kernel<<<1, 256, 0, stream>>>(counts, rowptr, cursor);
        scatter_kernel<<<edge_blocks, 256, 0, stream>>>(rows[s], cols[s], vals[s],
                                                        cursor, cols_s, vals_s, E);
        // atomic-free SpMM; pass 1 fuses +support1, +bias, relu
        spmm_csr_kernel<<<spmm_blocks, 256, 0, stream>>>(rowptr, cols_s, vals_s,
                                                         pre, bias, out, s);
    }
}

// Round 4
// 695.331 us; speedup vs baseline: 2.5471x; 1.5919x over previous
//
#include <hip/hip_runtime.h>

// GCN layer: relu(A1·(xW1) + A2·(xW2) + b), B=4, N=50000, F=64, E=800000.
// All float tensors fp32; indices int32.
#define NB 4
#define NN 50000
#define FF 64
#define SCAN_BLOCKS ((NN + 255) / 256)   // 196

// ---------------- GEMM: pre[n][b][f] = sum_k x[b][n][k] * W[k][f] ----------
// Batch-INTERLEAVED output layout so one edge gather touches one contiguous
// 1024 B block (4 batches x 64 feats). Grid: (NN/16, NB).
__global__ void gemm_xw_batched(const float* __restrict__ x,
                                const float* __restrict__ W,
                                float* __restrict__ pre) {
    __shared__ float Ws[FF][FF];   // 16 KB
    __shared__ float xs[4][FF];
    const int tid = threadIdx.x;
    const int b = blockIdx.y;
#pragma unroll
    for (int i = 0; i < 16; ++i) {
        int idx = tid + i * 256;
        Ws[idx >> 6][idx & 63] = W[idx];
    }
    const int r = tid >> 6;        // 0..3
    const int f = tid & 63;
    const int base = blockIdx.x * 16;
    const float* xb = x + (size_t)b * NN * FF;
#pragma unroll
    for (int g = 0; g < 4; ++g) {
        const int row = base + g * 4 + r;
        __syncthreads();
        xs[r][f] = xb[(size_t)row * FF + f];
        __syncthreads();
        float a = 0.f;
#pragma unroll
        for (int k = 0; k < FF; ++k) a += xs[r][k] * Ws[k][f];
        pre[((size_t)row * NB + b) * FF + f] = a;   // contiguous 256 B per wave
    }
}

// ---------------- CSR build: histogram -> hierarchical scan -> scatter ------
__global__ void hist_kernel(const int* __restrict__ rows, int* __restrict__ counts, int E) {
    const int e = blockIdx.x * blockDim.x + threadIdx.x;
    if (e < E) atomicAdd(&counts[rows[e]], 1);
}

// Stage 1: per-block exclusive scan of 256 counts; emit block totals.
__global__ void scan_partial(const int* __restrict__ counts,
                             int* __restrict__ excl, int* __restrict__ blocksum) {
    __shared__ int buf[256];
    const int tid = threadIdx.x;
    const int i = blockIdx.x * 256 + tid;
    const int v = (i < NN) ? counts[i] : 0;
    buf[tid] = v;
    __syncthreads();
#pragma unroll
    for (int off = 1; off < 256; off <<= 1) {
        int t = (tid >= off) ? buf[tid - off] : 0;
        __syncthreads();
        buf[tid] += t;
        __syncthreads();
    }
    if (i < NN) excl[i] = buf[tid] - v;
    if (tid == 255) blocksum[blockIdx.x] = buf[255];
}

// Stage 2: single block scans the 196 block totals (exclusive, in place);
// writes rowptr[NN] = E.
__global__ void scan_sums(int* __restrict__ blocksum, int* __restrict__ rowptr) {
    __shared__ int buf[256];
    const int tid = threadIdx.x;
    const int v = (tid < SCAN_BLOCKS) ? blocksum[tid] : 0;
    buf[tid] = v;
    __syncthreads();
#pragma unroll
    for (int off = 1; off < 256; off <<= 1) {
        int t = (tid >= off) ? buf[tid - off] : 0;
        __syncthreads();
        buf[tid] += t;
        __syncthreads();
    }
    if (tid < SCAN_BLOCKS) blocksum[tid] = buf[tid] - v;
    if (tid == 255) rowptr[NN] = buf[255];
}

// Stage 3: add block offsets; write rowptr and cursor.
__global__ void scan_add(const int* __restrict__ excl, const int* __restrict__ blocksum,
                         int* __restrict__ rowptr, int* __restrict__ cursor) {
    const int i = blockIdx.x * 256 + threadIdx.x;
    if (i < NN) {
        const int v = excl[i] + blocksum[blockIdx.x];
        rowptr[i] = v;
        cursor[i] = v;
    }
}

__global__ void scatter_kernel(const int* __restrict__ rows, const int* __restrict__ cols,
                               const float* __restrict__ vals, int* __restrict__ cursor,
                               int* __restrict__ cols_s, float* __restrict__ vals_s, int E) {
    const int e = blockIdx.x * blockDim.x + threadIdx.x;
    if (e >= E) return;
    const int pos = atomicAdd(&cursor[rows[e]], 1);
    cols_s[pos] = cols[e];
    vals_s[pos] = vals[e];
}

// ---------------- SpMM (CSR, atomic-free) -----------------------------------
// One 64-lane group per row; lane = feature. 4 accumulators = 4 batches.
// pass 0: out[b][r][f]  = sum            (support 1, covers every row)
// pass 1: out[b][r][f] += sum, +bias, relu (support 2, final)
__global__ void spmm_csr_kernel(const int* __restrict__ rowptr,
                                const int* __restrict__ cols_s,
                                const float* __restrict__ vals_s,
                                const float* __restrict__ pre,   // [N][4][64]
                                const float* __restrict__ bias,
                                float* __restrict__ out,         // [B][N][64]
                                int pass) {
    const int tid = blockIdx.x * blockDim.x + threadIdx.x;
    const int r = tid >> 6;
    if (r >= NN) return;
    const int f = tid & 63;
    float a0 = 0.f, a1 = 0.f, a2 = 0.f, a3 = 0.f;
    const int beg = rowptr[r], end = rowptr[r + 1];
    for (int j = beg; j < end; ++j) {
        const int c = cols_s[j];
        const float v = vals_s[j];
        const float* p = pre + (size_t)c * (NB * FF) + f;   // 1024 B block
        a0 += v * p[0];
        a1 += v * p[64];
        a2 += v * p[128];
        a3 += v * p[192];
    }
    const size_t o0 = (size_t)r * FF + f;
    const size_t s = (size_t)NN * FF;
    if (pass == 0) {
        out[o0] = a0; out[o0 + s] = a1; out[o0 + 2 * s] = a2; out[o0 + 3 * s] = a3;
    } else {
        const float bf = bias[f];
        float t0 = out[o0] + a0 + bf;
        float t1 = out[o0 + s] + a1 + bf;
        float t2 = out[o0 + 2 * s] + a2 + bf;
        float t3 = out[o0 + 3 * s] + a3 + bf;
        out[o0] = t0 > 0.f ? t0 : 0.f;
        out[o0 + s] = t1 > 0.f ? t1 : 0.f;
        out[o0 + 2 * s] = t2 > 0.f ? t2 : 0.f;
        out[o0 + 3 * s] = t3 > 0.f ? t3 : 0.f;
    }
}

extern "C" void kernel_launch(void* const* d_in, const int* in_sizes, int n_in,
                              void* d_out, int out_size, void* d_ws, size_t ws_size,
                              hipStream_t stream) {
    const float* x    = (const float*)d_in[0];
    const int*   rows[2] = { (const int*)d_in[1], (const int*)d_in[4] };
    const int*   cols[2] = { (const int*)d_in[2], (const int*)d_in[5] };
    const float* vals[2] = { (const float*)d_in[3], (const float*)d_in[6] };
    const float* Wm[2]   = { (const float*)d_in[7], (const float*)d_in[8] };
    const float* bias = (const float*)d_in[9];
    float* out = (float*)d_out;

    const int E = in_sizes[1];

    // Workspace layout (256 B aligned):
    //   pre: 51.2 MB | counts, excl, rowptr, cursor: NN ints | blocksum | cols_s, vals_s: E each
    char* w = (char*)d_ws;
    auto align = [](size_t v) { return (v + 255) & ~(size_t)255; };
    float* pre      = (float*)w;                     w += align((size_t)NN * NB * FF * 4);
    int*   counts   = (int*)w;                       w += align((size_t)NN * 4);
    int*   excl     = (int*)w;                       w += align((size_t)NN * 4);
    int*   rowptr   = (int*)w;                       w += align(((size_t)NN + 1) * 4);
    int*   cursor   = (int*)w;                       w += align((size_t)NN * 4);
    int*   blocksum = (int*)w;                       w += align((size_t)SCAN_BLOCKS * 4);
    int*   cols_s   = (int*)w;                       w += align((size_t)E * 4);
    float* vals_s   = (float*)w;

    const dim3 gemm_grid(NN / 16, NB);
    const int  edge_blocks = (E + 255) / 256;
    const int  spmm_blocks = (NN * FF + 255) / 256;   // NN/4 row-quads

    for (int s = 0; s < 2; ++s) {
        // dense: pre[n][b][f] = x[b][n][:] . W_s
        gemm_xw_batched<<<gemm_grid, 256, 0, stream>>>(x, Wm[s], pre);
        // CSR build for support s
        hipMemsetAsync(counts, 0, (size_t)NN * 4, stream);
        hist_kernel<<<edge_blocks, 256, 0, stream>>>(rows[s], counts, E);
        scan_partial<<<SCAN_BLOCKS, 256, 0, stream>>>(counts, excl, blocksum);
        scan_sums<<<1, 256, 0, stream>>>(blocksum, rowptr);
        scan_add<<<SCAN_BLOCKS, 256, 0, stream>>>(excl, blocksum, rowptr, cursor);
        scatter_kernel<<<edge_blocks, 256, 0, stream>>>(rows[s], cols[s], vals[s],
                                                        cursor, cols_s, vals_s, E);
        // atomic-free SpMM; pass 1 fuses +support1, +bias, relu
        spmm_csr_kernel<<<spmm_blocks, 256, 0, stream>>>(rowptr, cols_s, vals_s,
                                                         pre, bias, out, s);
    }
}

// Round 5
// 661.751 us; speedup vs baseline: 2.6763x; 1.0507x over previous
//
#include <hip/hip_runtime.h>

// GCN layer: relu(A1·(xW1) + A2·(xW2) + b), B=4, N=50000, F=64, E=800000.
// fp32 tensors, int32 indices.
// Layouts: pre[n][f] = float4 over the 4 batches (one dwordx4 per gather lane).
//          CSR for both supports concatenated: counts/rowptr/cursor have 2N
//          entries (support 1 then support 2), edges packed as int2{col,val}.
#define NB 4
#define NN 50000
#define FF 64
#define NN2 (2 * NN)
#define SCAN_BLOCKS ((NN2 + 255) / 256)   // 391

// ---------------- GEMM: pre[n][f] = {sum_k x[b][n][k] W[k][f]}_{b=0..3} -----
// Block = 256 threads (4 rows x 64 f), 16 rows/block via g-loop. Each thread
// computes all 4 batches and writes one float4 (wave writes 1024 B contig).
__global__ void gemm_xw(const float* __restrict__ x, const float* __restrict__ W,
                        float4* __restrict__ pre) {
    __shared__ float Ws[FF][FF];       // 16 KB
    __shared__ float xs[NB][4][FF];    // 4 KB
    const int tid = threadIdx.x;
#pragma unroll
    for (int i = 0; i < 16; ++i) {
        int idx = tid + i * 256;
        Ws[idx >> 6][idx & 63] = W[idx];
    }
    const int r = tid >> 6, f = tid & 63;
    const int base = blockIdx.x * 16;
#pragma unroll
    for (int g = 0; g < 4; ++g) {
        const int row = base + g * 4 + r;
        __syncthreads();
#pragma unroll
        for (int b = 0; b < NB; ++b)
            xs[b][r][f] = x[((size_t)b * NN + row) * FF + f];   // 256 B coalesced
        __syncthreads();
        float a0 = 0.f, a1 = 0.f, a2 = 0.f, a3 = 0.f;
#pragma unroll
        for (int k = 0; k < FF; ++k) {
            const float w = Ws[k][f];                 // conflict-free
            a0 += xs[0][r][k] * w;                    // broadcast reads
            a1 += xs[1][r][k] * w;
            a2 += xs[2][r][k] * w;
            a3 += xs[3][r][k] * w;
        }
        pre[(size_t)row * FF + f] = make_float4(a0, a1, a2, a3);
    }
}

// ---------------- CSR build (both supports, concatenated) -------------------
__global__ void hist_both(const int* __restrict__ r1, const int* __restrict__ r2,
                          int* __restrict__ counts, int E) {
    const int e = blockIdx.x * blockDim.x + threadIdx.x;
    if (e < E)              atomicAdd(&counts[r1[e]], 1);
    else if (e < 2 * E)     atomicAdd(&counts[NN + r2[e - E]], 1);
}

__global__ void scan_partial(const int* __restrict__ counts,
                             int* __restrict__ excl, int* __restrict__ blocksum) {
    __shared__ int buf[256];
    const int tid = threadIdx.x;
    const int i = blockIdx.x * 256 + tid;
    const int v = (i < NN2) ? counts[i] : 0;
    buf[tid] = v;
    __syncthreads();
#pragma unroll
    for (int off = 1; off < 256; off <<= 1) {
        int t = (tid >= off) ? buf[tid - off] : 0;
        __syncthreads();
        buf[tid] += t;
        __syncthreads();
    }
    if (i < NN2) excl[i] = buf[tid] - v;
    if (tid == 255) blocksum[blockIdx.x] = buf[255];
}

// 512 threads; scans the 391 block sums; writes rowptr[2N] = 2E.
__global__ void scan_sums(int* __restrict__ blocksum, int* __restrict__ rowptr) {
    __shared__ int buf[512];
    const int tid = threadIdx.x;
    const int v = (tid < SCAN_BLOCKS) ? blocksum[tid] : 0;
    buf[tid] = v;
    __syncthreads();
#pragma unroll
    for (int off = 1; off < 512; off <<= 1) {
        int t = (tid >= off) ? buf[tid - off] : 0;
        __syncthreads();
        buf[tid] += t;
        __syncthreads();
    }
    if (tid < SCAN_BLOCKS) blocksum[tid] = buf[tid] - v;
    if (tid == 511) rowptr[NN2] = buf[511];
}

__global__ void scan_add(const int* __restrict__ excl, const int* __restrict__ blocksum,
                         int* __restrict__ rowptr, int* __restrict__ cursor) {
    const int i = blockIdx.x * 256 + threadIdx.x;
    if (i < NN2) {
        const int v = excl[i] + blocksum[blockIdx.x];
        rowptr[i] = v;
        cursor[i] = v;
    }
}

__global__ void scatter_both(const int* __restrict__ r1, const int* __restrict__ c1,
                             const float* __restrict__ v1,
                             const int* __restrict__ r2, const int* __restrict__ c2,
                             const float* __restrict__ v2,
                             int* __restrict__ cursor, int2* __restrict__ cv, int E) {
    const int e = blockIdx.x * blockDim.x + threadIdx.x;
    int row, col; float val;
    if (e < E)          { row = r1[e];          col = c1[e];     val = v1[e]; }
    else if (e < 2 * E) { row = NN + r2[e - E]; col = c2[e - E]; val = v2[e - E]; }
    else return;
    const int pos = atomicAdd(&cursor[row], 1);
    cv[pos] = make_int2(col, __float_as_int(val));   // one 8 B store
}

// ---------------- SpMM (CSR, atomic-free, float4 gather, unroll 4) ----------
// One 64-lane group per row; lane = feature; float4 = 4 batches.
// pass 0: out = sum (support 1). pass 1: out += sum, +bias, relu (support 2).
__global__ void spmm_csr(const int* __restrict__ rowptr, const int2* __restrict__ cv,
                         const float4* __restrict__ pre, const float* __restrict__ bias,
                         float* __restrict__ out, int pass) {
    const int tid = blockIdx.x * blockDim.x + threadIdx.x;
    const int r = tid >> 6;
    if (r >= NN) return;
    const int f = tid & 63;
    const int beg = rowptr[pass * NN + r], end = rowptr[pass * NN + r + 1];
    float a0 = 0.f, a1 = 0.f, a2 = 0.f, a3 = 0.f;
    int j = beg;
    for (; j + 4 <= end; j += 4) {                    // 4 independent gathers in flight
        const int2 e0 = cv[j], e1 = cv[j + 1], e2 = cv[j + 2], e3 = cv[j + 3];
        const float4 p0 = pre[e0.x * FF + f];
        const float4 p1 = pre[e1.x * FF + f];
        const float4 p2 = pre[e2.x * FF + f];
        const float4 p3 = pre[e3.x * FF + f];
        const float v0 = __int_as_float(e0.y), v1 = __int_as_float(e1.y);
        const float v2 = __int_as_float(e2.y), v3 = __int_as_float(e3.y);
        a0 += v0 * p0.x + v1 * p1.x + v2 * p2.x + v3 * p3.x;
        a1 += v0 * p0.y + v1 * p1.y + v2 * p2.y + v3 * p3.y;
        a2 += v0 * p0.z + v1 * p1.z + v2 * p2.z + v3 * p3.z;
        a3 += v0 * p0.w + v1 * p1.w + v2 * p2.w + v3 * p3.w;
    }
    for (; j < end; ++j) {
        const int2 e = cv[j];
        const float4 p = pre[e.x * FF + f];
        const float v = __int_as_float(e.y);
        a0 += v * p.x; a1 += v * p.y; a2 += v * p.z; a3 += v * p.w;
    }
    const size_t o = (size_t)r * FF + f;
    const size_t s = (size_t)NN * FF;
    if (pass == 0) {
        out[o] = a0; out[o + s] = a1; out[o + 2 * s] = a2; out[o + 3 * s] = a3;
    } else {
        const float bf = bias[f];
        float t0 = out[o] + a0 + bf;
        float t1 = out[o + s] + a1 + bf;
        float t2 = out[o + 2 * s] + a2 + bf;
        float t3 = out[o + 3 * s] + a3 + bf;
        out[o]         = t0 > 0.f ? t0 : 0.f;
        out[o + s]     = t1 > 0.f ? t1 : 0.f;
        out[o + 2 * s] = t2 > 0.f ? t2 : 0.f;
        out[o + 3 * s] = t3 > 0.f ? t3 : 0.f;
    }
}

extern "C" void kernel_launch(void* const* d_in, const int* in_sizes, int n_in,
                              void* d_out, int out_size, void* d_ws, size_t ws_size,
                              hipStream_t stream) {
    const float* x    = (const float*)d_in[0];
    const int*   rows1 = (const int*)d_in[1];
    const int*   cols1 = (const int*)d_in[2];
    const float* vals1 = (const float*)d_in[3];
    const int*   rows2 = (const int*)d_in[4];
    const int*   cols2 = (const int*)d_in[5];
    const float* vals2 = (const float*)d_in[6];
    const float* W1   = (const float*)d_in[7];
    const float* W2   = (const float*)d_in[8];
    const float* bias = (const float*)d_in[9];
    float* out = (float*)d_out;

    const int E = in_sizes[1];

    // Workspace (~66 MB): pre 51.2 MB | counts/excl/rowptr/cursor 400 KB ea |
    // blocksum | cv 12.8 MB
    char* w = (char*)d_ws;
    auto align = [](size_t v) { return (v + 255) & ~(size_t)255; };
    float4* pre      = (float4*)w;                   w += align((size_t)NN * FF * 16);
    int*    counts   = (int*)w;                      w += align((size_t)NN2 * 4);
    int*    excl     = (int*)w;                      w += align((size_t)NN2 * 4);
    int*    rowptr   = (int*)w;                      w += align(((size_t)NN2 + 1) * 4);
    int*    cursor   = (int*)w;                      w += align((size_t)NN2 * 4);
    int*    blocksum = (int*)w;                      w += align((size_t)SCAN_BLOCKS * 4);
    int2*   cv       = (int2*)w;

    const int gemm_blocks = NN / 16;                  // 3125
    const int edge2_blocks = (2 * E + 255) / 256;     // 6250
    const int spmm_blocks  = (NN * FF + 255) / 256;   // 12500

    // Build both CSRs once (concatenated).
    hipMemsetAsync(counts, 0, (size_t)NN2 * 4, stream);
    hist_both<<<edge2_blocks, 256, 0, stream>>>(rows1, rows2, counts, E);
    scan_partial<<<SCAN_BLOCKS, 256, 0, stream>>>(counts, excl, blocksum);
    scan_sums<<<1, 512, 0, stream>>>(blocksum, rowptr);
    scan_add<<<SCAN_BLOCKS, 256, 0, stream>>>(excl, blocksum, rowptr, cursor);
    scatter_both<<<edge2_blocks, 256, 0, stream>>>(rows1, cols1, vals1,
                                                   rows2, cols2, vals2, cursor, cv, E);

    // Support 1: pre = xW1; out = A1*pre.
    gemm_xw<<<gemm_blocks, 256, 0, stream>>>(x, W1, pre);
    spmm_csr<<<spmm_blocks, 256, 0, stream>>>(rowptr, cv, pre, bias, out, 0);
    // Support 2: pre = xW2; out = relu(out + A2*pre + b).
    gemm_xw<<<gemm_blocks, 256, 0, stream>>>(x, W2, pre);
    spmm_csr<<<spmm_blocks, 256, 0, stream>>>(rowptr, cv, pre, bias, out, 1);
}

// Round 6
// 418.739 us; speedup vs baseline: 4.2295x; 1.5803x over previous
//
#include <hip/hip_runtime.h>
#include <hip/hip_fp16.h>

// GCN layer: relu(A1·(xW1) + A2·(xW2) + b), B=4, N=50000, F=64, E=800000.
// fp32 in/out, int32 indices. pre stored fp16 (gather operand only; fp32 accum).
// pre[n][f] = 4 halves (batches) = 8 B -> one dwordx2 per gather lane.
// CSR concatenated for both supports (2N rows). Edge ranks captured in the
// histogram pass -> scatter is atomic-free.
#define NB 4
#define NN 50000
#define FF 64
#define NN2 (2 * NN)
#define SCAN_BLOCKS ((NN2 + 255) / 256)   // 391

// ---------------- fused GEMM: pre{1,2}[n][f] = half4{ x[b][n][:]·W{1,2}[:,f] } ---
__global__ void gemm_xw2(const float* __restrict__ x,
                         const float* __restrict__ W1, const float* __restrict__ W2,
                         uint2* __restrict__ pre1, uint2* __restrict__ pre2) {
    __shared__ float Ws1[FF][FF];      // 16 KB
    __shared__ float Ws2[FF][FF];      // 16 KB
    __shared__ float xs[NB][4][FF];    // 4 KB
    const int tid = threadIdx.x;
#pragma unroll
    for (int i = 0; i < 16; ++i) {
        int idx = tid + i * 256;
        Ws1[idx >> 6][idx & 63] = W1[idx];
        Ws2[idx >> 6][idx & 63] = W2[idx];
    }
    const int r = tid >> 6, f = tid & 63;
    const int base = blockIdx.x * 16;
#pragma unroll
    for (int g = 0; g < 4; ++g) {
        const int row = base + g * 4 + r;
        __syncthreads();
#pragma unroll
        for (int b = 0; b < NB; ++b)
            xs[b][r][f] = x[((size_t)b * NN + row) * FF + f];   // coalesced
        __syncthreads();
        float p0 = 0.f, p1 = 0.f, p2 = 0.f, p3 = 0.f;   // support 1, batches 0..3
        float q0 = 0.f, q1 = 0.f, q2 = 0.f, q3 = 0.f;   // support 2
#pragma unroll
        for (int k = 0; k < FF; ++k) {
            const float w1 = Ws1[k][f], w2 = Ws2[k][f];          // conflict-free
            const float x0 = xs[0][r][k], x1 = xs[1][r][k];      // broadcast
            const float x2 = xs[2][r][k], x3 = xs[3][r][k];
            p0 += x0 * w1; p1 += x1 * w1; p2 += x2 * w1; p3 += x3 * w1;
            q0 += x0 * w2; q1 += x1 * w2; q2 += x2 * w2; q3 += x3 * w2;
        }
        const size_t o = (size_t)row * FF + f;
        __half2 h01 = __floats2half2_rn(p0, p1), h23 = __floats2half2_rn(p2, p3);
        pre1[o] = make_uint2(*(unsigned*)&h01, *(unsigned*)&h23);   // 512 B/wave
        h01 = __floats2half2_rn(q0, q1); h23 = __floats2half2_rn(q2, q3);
        pre2[o] = make_uint2(*(unsigned*)&h01, *(unsigned*)&h23);
    }
}

// ---------------- CSR build ------------------------------------------------
// Histogram + per-edge rank (the atomic's return value). rank[] aliases pre1
// storage (disjoint lifetime: rank dies at scatter, pre1 born at gemm).
__global__ void hist_rank(const int* __restrict__ r1, const int* __restrict__ r2,
                          int* __restrict__ counts, int* __restrict__ rank, int E) {
    const int e = blockIdx.x * blockDim.x + threadIdx.x;
    if (e < E)          rank[e] = atomicAdd(&counts[r1[e]], 1);
    else if (e < 2 * E) rank[e] = atomicAdd(&counts[NN + r2[e - E]], 1);
}

// Stage 1: per-block exclusive scan of counts -> rowptr (partial) + blocksum.
__global__ void scan_partial(const int* __restrict__ counts,
                             int* __restrict__ rowptr, int* __restrict__ blocksum) {
    __shared__ int buf[256];
    const int tid = threadIdx.x;
    const int i = blockIdx.x * 256 + tid;
    const int v = (i < NN2) ? counts[i] : 0;
    buf[tid] = v;
    __syncthreads();
#pragma unroll
    for (int off = 1; off < 256; off <<= 1) {
        int t = (tid >= off) ? buf[tid - off] : 0;
        __syncthreads();
        buf[tid] += t;
        __syncthreads();
    }
    if (i < NN2) rowptr[i] = buf[tid] - v;
    if (tid == 255) blocksum[blockIdx.x] = buf[255];
}

// Stage 2: single 512-thread block scans the 391 block sums; rowptr[2N] = 2E.
__global__ void scan_sums(int* __restrict__ blocksum, int* __restrict__ rowptr) {
    __shared__ int buf[512];
    const int tid = threadIdx.x;
    const int v = (tid < SCAN_BLOCKS) ? blocksum[tid] : 0;
    buf[tid] = v;
    __syncthreads();
#pragma unroll
    for (int off = 1; off < 512; off <<= 1) {
        int t = (tid >= off) ? buf[tid - off] : 0;
        __syncthreads();
        buf[tid] += t;
        __syncthreads();
    }
    if (tid < SCAN_BLOCKS) blocksum[tid] = buf[tid] - v;
    if (tid == 511) rowptr[NN2] = buf[511];
}

// Stage 3: add block offsets in place.
__global__ void scan_add(int* __restrict__ rowptr, const int* __restrict__ blocksum) {
    const int i = blockIdx.x * 256 + threadIdx.x;
    if (i < NN2) rowptr[i] += blocksum[blockIdx.x];
}

// Atomic-free scatter: pos = rowptr[row] + rank[e].
__global__ void scatter_ranked(const int* __restrict__ r1, const int* __restrict__ c1,
                               const float* __restrict__ v1,
                               const int* __restrict__ r2, const int* __restrict__ c2,
                               const float* __restrict__ v2,
                               const int* __restrict__ rowptr, const int* __restrict__ rank,
                               int2* __restrict__ cv, int E) {
    const int e = blockIdx.x * blockDim.x + threadIdx.x;
    int row, col; float val;
    if (e < E)          { row = r1[e];          col = c1[e];     val = v1[e]; }
    else if (e < 2 * E) { row = NN + r2[e - E]; col = c2[e - E]; val = v2[e - E]; }
    else return;
    cv[rowptr[row] + rank[e]] = make_int2(col, __float_as_int(val));
}

// ---------------- fused SpMM: out = relu(A1·pre1 + A2·pre2 + b) -------------
__device__ __forceinline__ void acc_seg(int beg, int end,
                                        const int2* __restrict__ cv,
                                        const uint2* __restrict__ pre, int f,
                                        float& a0, float& a1, float& a2, float& a3) {
    int j = beg;
    for (; j + 4 <= end; j += 4) {                 // 4 independent gathers in flight
        const int2 e0 = cv[j], e1 = cv[j + 1], e2 = cv[j + 2], e3 = cv[j + 3];
        const uint2 g0 = pre[(size_t)e0.x * FF + f];
        const uint2 g1 = pre[(size_t)e1.x * FF + f];
        const uint2 g2 = pre[(size_t)e2.x * FF + f];
        const uint2 g3 = pre[(size_t)e3.x * FF + f];
        const float v0 = __int_as_float(e0.y), v1 = __int_as_float(e1.y);
        const float v2 = __int_as_float(e2.y), v3 = __int_as_float(e3.y);
        float2 a, b;
        a = __half22float2(*(const __half2*)&g0.x); b = __half22float2(*(const __half2*)&g0.y);
        a0 += v0 * a.x; a1 += v0 * a.y; a2 += v0 * b.x; a3 += v0 * b.y;
        a = __half22float2(*(const __half2*)&g1.x); b = __half22float2(*(const __half2*)&g1.y);
        a0 += v1 * a.x; a1 += v1 * a.y; a2 += v1 * b.x; a3 += v1 * b.y;
        a = __half22float2(*(const __half2*)&g2.x); b = __half22float2(*(const __half2*)&g2.y);
        a0 += v2 * a.x; a1 += v2 * a.y; a2 += v2 * b.x; a3 += v2 * b.y;
        a = __half22float2(*(const __half2*)&g3.x); b = __half22float2(*(const __half2*)&g3.y);
        a0 += v3 * a.x; a1 += v3 * a.y; a2 += v3 * b.x; a3 += v3 * b.y;
    }
    for (; j < end; ++j) {
        const int2 e = cv[j];
        const uint2 g = pre[(size_t)e.x * FF + f];
        const float v = __int_as_float(e.y);
        const float2 a = __half22float2(*(const __half2*)&g.x);
        const float2 b = __half22float2(*(const __half2*)&g.y);
        a0 += v * a.x; a1 += v * a.y; a2 += v * b.x; a3 += v * b.y;
    }
}

__global__ void spmm_fused(const int* __restrict__ rowptr, const int2* __restrict__ cv,
                           const uint2* __restrict__ pre1, const uint2* __restrict__ pre2,
                           const float* __restrict__ bias, float* __restrict__ out) {
    const int tid = blockIdx.x * blockDim.x + threadIdx.x;
    const int r = tid >> 6;
    if (r >= NN) return;
    const int f = tid & 63;
    float a0 = 0.f, a1 = 0.f, a2 = 0.f, a3 = 0.f;
    acc_seg(rowptr[r],      rowptr[r + 1],      cv, pre1, f, a0, a1, a2, a3);
    acc_seg(rowptr[NN + r], rowptr[NN + r + 1], cv, pre2, f, a0, a1, a2, a3);
    const float bf = bias[f];
    a0 += bf; a1 += bf; a2 += bf; a3 += bf;
    const size_t o = (size_t)r * FF + f;
    const size_t s = (size_t)NN * FF;
    out[o]         = a0 > 0.f ? a0 : 0.f;
    out[o + s]     = a1 > 0.f ? a1 : 0.f;
    out[o + 2 * s] = a2 > 0.f ? a2 : 0.f;
    out[o + 3 * s] = a3 > 0.f ? a3 : 0.f;
}

extern "C" void kernel_launch(void* const* d_in, const int* in_sizes, int n_in,
                              void* d_out, int out_size, void* d_ws, size_t ws_size,
                              hipStream_t stream) {
    const float* x     = (const float*)d_in[0];
    const int*   rows1 = (const int*)d_in[1];
    const int*   cols1 = (const int*)d_in[2];
    const float* vals1 = (const float*)d_in[3];
    const int*   rows2 = (const int*)d_in[4];
    const int*   cols2 = (const int*)d_in[5];
    const float* vals2 = (const float*)d_in[6];
    const float* W1    = (const float*)d_in[7];
    const float* W2    = (const float*)d_in[8];
    const float* bias  = (const float*)d_in[9];
    float* out = (float*)d_out;

    const int E = in_sizes[1];

    // Workspace (~65 MB): pre1 25.6 | pre2 25.6 | cv 12.8 | counts/rowptr 400K ea.
    // rank[2E] (6.4 MB) ALIASES pre1: rank lifetime ends at scatter_ranked,
    // pre1 lifetime starts at gemm_xw2 (later on the same stream).
    char* w = (char*)d_ws;
    auto align = [](size_t v) { return (v + 255) & ~(size_t)255; };
    uint2* pre1     = (uint2*)w;                 w += align((size_t)NN * FF * 8);
    uint2* pre2     = (uint2*)w;                 w += align((size_t)NN * FF * 8);
    int2*  cv       = (int2*)w;                  w += align((size_t)2 * E * 8);
    int*   counts   = (int*)w;                   w += align((size_t)NN2 * 4);
    int*   rowptr   = (int*)w;                   w += align(((size_t)NN2 + 1) * 4);
    int*   blocksum = (int*)w;                   w += align((size_t)SCAN_BLOCKS * 4);
    int*   rank     = (int*)pre1;                // alias, see above

    const int gemm_blocks  = NN / 16;                 // 3125
    const int edge2_blocks = (2 * E + 255) / 256;     // 6250
    const int spmm_blocks  = (NN * FF + 255) / 256;   // 12500

    hipMemsetAsync(counts, 0, (size_t)NN2 * 4, stream);
    hist_rank<<<edge2_blocks, 256, 0, stream>>>(rows1, rows2, counts, rank, E);
    scan_partial<<<SCAN_BLOCKS, 256, 0, stream>>>(counts, rowptr, blocksum);
    scan_sums<<<1, 512, 0, stream>>>(blocksum, rowptr);
    scan_add<<<SCAN_BLOCKS, 256, 0, stream>>>(rowptr, blocksum);
    scatter_ranked<<<edge2_blocks, 256, 0, stream>>>(rows1, cols1, vals1,
                                                     rows2, cols2, vals2,
                                                     rowptr, rank, cv, E);
    gemm_xw2<<<gemm_blocks, 256, 0, stream>>>(x, W1, W2, pre1, pre2);
    spmm_fused<<<spmm_blocks, 256, 0, stream>>>(rowptr, cv, pre1, pre2, bias, out);
}